// Round 8
// baseline (553.500 us; speedup 1.0000x reference)
//
#include <hip/hip_runtime.h>

typedef _Float16 f16;
typedef _Float16 f16x8 __attribute__((ext_vector_type(8)));
typedef float f32x4 __attribute__((ext_vector_type(4)));

static constexpr int N_ = 8, C_ = 256, c_ = 128, L_ = 4096;

#define DEVI __device__ __forceinline__

DEVI f16x8 ldg8(const f16* p){ return *reinterpret_cast<const f16x8*>(p); }
DEVI f32x4 mfma16(f16x8 a, f16x8 b, f32x4 c){
  return __builtin_amdgcn_mfma_f32_16x16x32_f16(a, b, c, 0, 0, 0);
}
DEVI float silu(float x){ return x / (1.f + __expf(-x)); }

// ---------------- weight fp32 -> fp16 ----------------
__global__ __launch_bounds__(256) void prep_weights(const float* __restrict__ wq,
    const float* __restrict__ wk, const float* __restrict__ wv,
    const float* __restrict__ wo, f16* __restrict__ dst){
  int i = blockIdx.x * 256 + threadIdx.x;   // 131072 total
  int off = i & 32767;
  const float* s;
  switch (i >> 15){
    case 0:  s = wq; break;
    case 1:  s = wk; break;
    case 2:  s = wv; break;
    default: s = wo; break;
  }
  dst[i] = (f16)s[off];
}

// ---------------- group-norm stats ----------------
__global__ __launch_bounds__(256) void gn_stats(const float* __restrict__ x,
                                                float* __restrict__ st){
  int n = blockIdx.x >> 5, g = blockIdx.x & 31;
  const float* base = x + (size_t)(n * C_ + g * 8) * L_;   // 8 ch * 4096
  float s = 0.f, ss = 0.f;
  for (int it = 0; it < 32; ++it){
    float4 v = *reinterpret_cast<const float4*>(base + it * 1024 + threadIdx.x * 4);
    s  += v.x + v.y + v.z + v.w;
    ss += v.x * v.x + v.y * v.y + v.z * v.z + v.w * v.w;
  }
  #pragma unroll
  for (int m = 1; m <= 32; m <<= 1){ s += __shfl_xor(s, m); ss += __shfl_xor(ss, m); }
  __shared__ float red[8];
  int w = threadIdx.x >> 6;
  if ((threadIdx.x & 63) == 0){ red[w] = s; red[4 + w] = ss; }
  __syncthreads();
  if (threadIdx.x == 0){
    s  = red[0] + red[1] + red[2] + red[3];
    ss = red[4] + red[5] + red[6] + red[7];
    float mean = s * (1.f / 32768.f);
    float var  = ss * (1.f / 32768.f) - mean * mean;
    float2 o; o.x = mean; o.y = rsqrtf(var + 1e-5f);
    reinterpret_cast<float2*>(st)[blockIdx.x] = o;
  }
}

// ------------- GN apply + SiLU + transpose: x[N,C,L] f32 -> fT[N,L,C] f16 -------------
__global__ __launch_bounds__(256) void gn_apply(const float* __restrict__ x,
    const float* __restrict__ st, const float* __restrict__ gw,
    const float* __restrict__ gb, f16* __restrict__ fT){
  int n = blockIdx.z, c0 = blockIdx.y * 64, l0 = blockIdx.x * 64;
  __shared__ f16 tile[64][72];
  int t = threadIdx.x;
  int cr = t >> 4, lc = (t & 15) * 4;
  const float* xb = x + (size_t)(n * C_ + c0) * L_ + l0;
  #pragma unroll
  for (int p = 0; p < 4; ++p){
    int cc = cr + p * 16;
    int ch = c0 + cc;
    float2 ms = reinterpret_cast<const float2*>(st)[n * 32 + (ch >> 3)];
    float w = gw[ch], b = gb[ch];
    float4 v = *reinterpret_cast<const float4*>(xb + (size_t)cc * L_ + lc);
    float f0 = (v.x - ms.x) * ms.y * w + b;
    float f1 = (v.y - ms.x) * ms.y * w + b;
    float f2 = (v.z - ms.x) * ms.y * w + b;
    float f3 = (v.w - ms.x) * ms.y * w + b;
    tile[cc][lc + 0] = (f16)silu(f0);
    tile[cc][lc + 1] = (f16)silu(f1);
    tile[cc][lc + 2] = (f16)silu(f2);
    tile[cc][lc + 3] = (f16)silu(f3);
  }
  __syncthreads();
  int lr = t >> 2, cq = (t & 3) * 16;
  f16 tmp[16];
  #pragma unroll
  for (int e = 0; e < 16; ++e) tmp[e] = tile[cq + e][lr];
  f16* o = fT + (size_t)(n * L_ + l0 + lr) * C_ + c0 + cq;
  *reinterpret_cast<f16x8*>(o)     = *reinterpret_cast<f16x8*>(tmp);
  *reinterpret_cast<f16x8*>(o + 8) = *reinterpret_cast<f16x8*>(tmp + 8);
}

// ------------- generic MFMA GEMM: D[i][j] = sum_k A[i][k]*B[j][k] (+epilogue) -------------
// EPI 1: f16 out, + bias[i]      (v projection)
// EPI 2: f32 out, + bias[i] + resid (output projection + residual)
// EPI 3: f16 out, fused q/k: j<128 -> outv+bias[j], j>=128 -> outv2+bias2[j-128]
template<int EPI>
__global__ __launch_bounds__(256) void proj(const f16* __restrict__ A, size_t a_nstr,
    const f16* __restrict__ B, size_t b_nstr, const float* __restrict__ bias,
    void* __restrict__ outv, size_t o_nstr, int ldo,
    const float* __restrict__ resid, size_t r_nstr, int Ks,
    const float* __restrict__ bias2, void* __restrict__ outv2){
  int n = blockIdx.z;
  int i0 = blockIdx.x * 64;
  int w  = threadIdx.x >> 6;
  int jw = blockIdx.y * 128 + w * 32;
  int lane = threadIdx.x & 63, l15 = lane & 15, g4 = lane >> 4;
  const f16* Ab = A + (size_t)n * a_nstr;
  const f16* Bb = B + (size_t)n * b_nstr;
  int K = Ks * 32;
  f32x4 acc[4][2];
  #pragma unroll
  for (int mf = 0; mf < 4; ++mf)
    #pragma unroll
    for (int nf = 0; nf < 2; ++nf) acc[mf][nf] = (f32x4){0.f, 0.f, 0.f, 0.f};

  for (int ks = 0; ks < Ks; ++ks){
    int kk = ks * 32 + 8 * g4;
    f16x8 a[4], b[2];
    #pragma unroll
    for (int mf = 0; mf < 4; ++mf)
      a[mf] = ldg8(Ab + (size_t)(i0 + 16 * mf + l15) * K + kk);
    #pragma unroll
    for (int nf = 0; nf < 2; ++nf)
      b[nf] = ldg8(Bb + (size_t)(jw + 16 * nf + l15) * K + kk);
    #pragma unroll
    for (int mf = 0; mf < 4; ++mf)
      #pragma unroll
      for (int nf = 0; nf < 2; ++nf)
        acc[mf][nf] = mfma16(a[mf], b[nf], acc[mf][nf]);
  }

  #pragma unroll
  for (int mf = 0; mf < 4; ++mf){
    #pragma unroll
    for (int nf = 0; nf < 2; ++nf){
      int j = jw + 16 * nf + l15;
      #pragma unroll
      for (int r = 0; r < 4; ++r){
        int i = i0 + 16 * mf + 4 * g4 + r;
        float v = acc[mf][nf][r];
        if (EPI == 1){
          ((f16*)outv)[(size_t)n * o_nstr + (size_t)i * ldo + j] = (f16)(v + bias[i]);
        } else if (EPI == 2){
          size_t oidx = (size_t)n * o_nstr + (size_t)i * ldo + j;
          ((float*)outv)[oidx] = v + bias[i] + resid[(size_t)n * r_nstr + (size_t)i * ldo + j];
        } else {  // EPI 3
          if (j < 128)
            ((f16*)outv)[(size_t)n * o_nstr + (size_t)i * ldo + j] = (f16)(v + bias[j]);
          else
            ((f16*)outv2)[(size_t)n * o_nstr + (size_t)i * ldo + (j - 128)] = (f16)(v + bias2[j - 128]);
        }
      }
    }
  }
}

// ------------- flash attention: Q[N,L,128], K[N,L,128], V[N,128,L] -> silu(O/l)[N,L,128] -------------
// Round-8 changes vs round 7 (same grid/tiles/swizzles):
//  (a) async-STAGE split: next tile's K/V global loads issued right after the
//      first barrier, overlapping compute; LDS write after the tail barrier.
//  (b) defer-max softmax (THR=8): per-lane max + wave-uniform __any test; the
//      4-shfl max reduce + O/l rescale run only when a row max grows by >8.
//      Row-sum shuffles removed entirely (per-lane partial, epilogue reduce).
__global__ __launch_bounds__(256) void flash(const f16* __restrict__ Qg,
    const f16* __restrict__ Kg, const f16* __restrict__ Vg, f16* __restrict__ Og){
  __shared__ char Ksh[16384];   // [64 j][128 d] f16, 16B-swizzled
  __shared__ char Vsh[16384];   // [128 d][64 j] f16, 16B-swizzled
  __shared__ char Psh[8192];    // 4 waves x [16 i][64 j] f16, swizzled
  int n = blockIdx.y;
  int q0 = blockIdx.x * 64;
  int tid = threadIdx.x;
  int w = tid >> 6, lane = tid & 63, l15 = lane & 15, g4 = lane >> 4;
  int qb = q0 + w * 16;

  const f16* Qn = Qg + (size_t)n * L_ * 128;
  const f16* Kn = Kg + (size_t)n * L_ * 128;
  const f16* Vn = Vg + (size_t)n * 128 * L_;

  f16x8 qf[4];
  #pragma unroll
  for (int ks = 0; ks < 4; ++ks)
    qf[ks] = ldg8(Qn + (size_t)(qb + l15) * 128 + ks * 32 + 8 * g4);

  f32x4 o[8];
  #pragma unroll
  for (int nf = 0; nf < 8; ++nf) o[nf] = (f32x4){0.f, 0.f, 0.f, 0.f};
  float mrow[4], lpart[4];
  #pragma unroll
  for (int r = 0; r < 4; ++r){ mrow[r] = -1e30f; lpart[r] = 0.f; }

  // prologue: stage tile 0 into registers
  float4 kreg[4], vreg[4];
  #pragma unroll
  for (int it = 0; it < 4; ++it){
    int cid = it * 256 + tid; int j = cid >> 4, c = cid & 15;
    kreg[it] = *reinterpret_cast<const float4*>(Kn + (size_t)j * 128 + c * 8);
  }
  #pragma unroll
  for (int it = 0; it < 4; ++it){
    int cid = it * 256 + tid; int d = cid >> 3, c = cid & 7;
    vreg[it] = *reinterpret_cast<const float4*>(Vn + (size_t)d * L_ + c * 8);
  }

  for (int t = 0; t < 64; ++t){
    // write staged regs -> LDS (prev compute finished at tail barrier)
    #pragma unroll
    for (int it = 0; it < 4; ++it){
      int cid = it * 256 + tid; int j = cid >> 4, c = cid & 15;
      *reinterpret_cast<float4*>(Ksh + j * 256 + ((c * 16) ^ ((j & 7) << 4))) = kreg[it];
    }
    #pragma unroll
    for (int it = 0; it < 4; ++it){
      int cid = it * 256 + tid; int d = cid >> 3, c = cid & 7;
      *reinterpret_cast<float4*>(Vsh + d * 128 + ((c * 16) ^ ((d & 7) << 4))) = vreg[it];
    }
    __syncthreads();

    // issue next tile's global loads; latency hides under compute below
    if (t + 1 < 64){
      #pragma unroll
      for (int it = 0; it < 4; ++it){
        int cid = it * 256 + tid; int j = cid >> 4, c = cid & 15;
        kreg[it] = *reinterpret_cast<const float4*>(Kn + (size_t)((t + 1) * 64 + j) * 128 + c * 8);
      }
      #pragma unroll
      for (int it = 0; it < 4; ++it){
        int cid = it * 256 + tid; int d = cid >> 3, c = cid & 7;
        vreg[it] = *reinterpret_cast<const float4*>(Vn + (size_t)d * L_ + (t + 1) * 64 + c * 8);
      }
    }

    // S = Q K^T : per wave 16 i x 64 j
    f32x4 s[4];
    #pragma unroll
    for (int nf = 0; nf < 4; ++nf) s[nf] = (f32x4){0.f, 0.f, 0.f, 0.f};
    #pragma unroll
    for (int ks = 0; ks < 4; ++ks){
      #pragma unroll
      for (int nf = 0; nf < 4; ++nf){
        int j = 16 * nf + l15;
        f16x8 kf = *reinterpret_cast<const f16x8*>(Ksh + j * 256 + ((64 * ks + 16 * g4) ^ ((j & 7) << 4)));
        s[nf] = mfma16(qf[ks], kf, s[nf]);
      }
    }

    // defer-max online softmax (row i = 4*g4 + r; 16 lanes sharing g4 hold the row)
    float pm[4];
    #pragma unroll
    for (int r = 0; r < 4; ++r)
      pm[r] = fmaxf(fmaxf(s[0][r], s[1][r]), fmaxf(s[2][r], s[3][r]));
    bool ex = (pm[0] > mrow[0] + 8.f) | (pm[1] > mrow[1] + 8.f) |
              (pm[2] > mrow[2] + 8.f) | (pm[3] > mrow[3] + 8.f);
    if (__any(ex)){
      #pragma unroll
      for (int r = 0; r < 4; ++r){
        float m = pm[r];
        m = fmaxf(m, __shfl_xor(m, 1));
        m = fmaxf(m, __shfl_xor(m, 2));
        m = fmaxf(m, __shfl_xor(m, 4));
        m = fmaxf(m, __shfl_xor(m, 8));
        float mn = fmaxf(mrow[r], m);
        float sc = __expf(mrow[r] - mn);
        mrow[r] = mn;
        lpart[r] *= sc;
        #pragma unroll
        for (int nf = 0; nf < 8; ++nf) o[nf][r] *= sc;
      }
    }
    #pragma unroll
    for (int nf = 0; nf < 4; ++nf)
      #pragma unroll
      for (int r = 0; r < 4; ++r)
        s[nf][r] = __expf(s[nf][r] - mrow[r]);
    #pragma unroll
    for (int r = 0; r < 4; ++r)
      lpart[r] += (s[0][r] + s[1][r]) + (s[2][r] + s[3][r]);

    // write P (f16) to this wave's LDS region [16 i][128B row]
    char* pb = Psh + w * 2048;
    #pragma unroll
    for (int nf = 0; nf < 4; ++nf)
      #pragma unroll
      for (int r = 0; r < 4; ++r){
        int i = 4 * g4 + r;
        int jj = 16 * nf + l15;
        *reinterpret_cast<f16*>(pb + i * 128 + ((2 * jj) ^ ((i & 7) << 4))) = (f16)s[nf][r];
      }

    // PV: O += P V
    #pragma unroll
    for (int ks = 0; ks < 2; ++ks){
      f16x8 pa = *reinterpret_cast<const f16x8*>(pb + l15 * 128 + ((64 * ks + 16 * g4) ^ ((l15 & 7) << 4)));
      #pragma unroll
      for (int nf = 0; nf < 8; ++nf){
        int d = 16 * nf + l15;
        f16x8 vf = *reinterpret_cast<const f16x8*>(Vsh + d * 128 + ((64 * ks + 16 * g4) ^ ((d & 7) << 4)));
        o[nf] = mfma16(pa, vf, o[nf]);
      }
    }
    __syncthreads();
  }

  // epilogue: reduce row-sum partials across the 16 lanes, then g = silu(O / l)
  float lrow[4];
  #pragma unroll
  for (int r = 0; r < 4; ++r){
    float rs = lpart[r];
    rs += __shfl_xor(rs, 1);
    rs += __shfl_xor(rs, 2);
    rs += __shfl_xor(rs, 4);
    rs += __shfl_xor(rs, 8);
    lrow[r] = rs;
  }
  f16* Ob = Og + (size_t)n * L_ * 128;
  #pragma unroll
  for (int r = 0; r < 4; ++r){
    float inv = 1.f / lrow[r];
    #pragma unroll
    for (int nf = 0; nf < 8; ++nf){
      float val = o[nf][r] * inv;
      Ob[(size_t)(qb + 4 * g4 + r) * 128 + 16 * nf + l15] = (f16)silu(val);
    }
  }
}

extern "C" void kernel_launch(void* const* d_in, const int* in_sizes, int n_in,
                              void* d_out, int out_size, void* d_ws, size_t ws_size,
                              hipStream_t stream){
  const float* x   = (const float*)d_in[0];
  const float* gnw = (const float*)d_in[1];
  const float* gnb = (const float*)d_in[2];
  const float* wq  = (const float*)d_in[3];
  const float* bq  = (const float*)d_in[4];
  const float* wk  = (const float*)d_in[5];
  const float* bk  = (const float*)d_in[6];
  const float* wv  = (const float*)d_in[7];
  const float* bv  = (const float*)d_in[8];
  const float* wo  = (const float*)d_in[9];
  const float* bo  = (const float*)d_in[10];
  float* out = (float*)d_out;

  char* ws = (char*)d_ws;
  f16* fT   = (f16*)(ws);                          // 16 MB  [N,L,C]
  f16* q    = (f16*)(ws + ((size_t)16 << 20));     // 8 MB   [N,L,128]
  f16* k    = (f16*)(ws + ((size_t)24 << 20));     // 8 MB   [N,L,128]
  f16* v    = (f16*)(ws + ((size_t)32 << 20));     // 8 MB   [N,128,L]
  f16* gbuf = (f16*)(ws + ((size_t)40 << 20));     // 8 MB   [N,L,128]
  f16* wh   = (f16*)(ws + ((size_t)48 << 20));     // 256 KB: wq|wk|wv|wo f16
  float* st = (float*)(ws + ((size_t)49 << 20));   // 2 KB

  prep_weights<<<512, 256, 0, stream>>>(wq, wk, wv, wo, wh);
  gn_stats<<<256, 256, 0, stream>>>(x, st);
  gn_apply<<<dim3(64, 4, 8), 256, 0, stream>>>(x, st, gnw, gnb, fT);

  // fused q,k: D[l][j] = sum_c fT[l][c] * [wq;wk][j][c], j in [0,256)
  proj<3><<<dim3(64, 2, 8), 256, 0, stream>>>(fT, (size_t)L_ * C_, wh, 0, bq,
                                              q, (size_t)L_ * c_, c_, nullptr, 0, 8, bk, k);
  // v: D[o][l] = sum_c wv[o][c] * fT[l][c]
  proj<1><<<dim3(2, 32, 8), 256, 0, stream>>>(wh + 65536, 0, fT, (size_t)L_ * C_, bv,
                                              v, (size_t)c_ * L_, L_, nullptr, 0, 8, nullptr, nullptr);
  flash<<<dim3(64, 8), 256, 0, stream>>>(q, k, v, gbuf);
  // out: D[o][l] = sum_d wo[o][d] * g[l][d] + bo[o] + x
  proj<2><<<dim3(4, 32, 8), 256, 0, stream>>>(wh + 98304, 0, gbuf, (size_t)L_ * c_, bo,
                                              out, (size_t)C_ * L_, L_, x, (size_t)C_ * L_, 4, nullptr, nullptr);
}

// Round 10
// 459.781 us; speedup vs baseline: 1.2038x; 1.2038x over previous
//
#include <hip/hip_runtime.h>

typedef _Float16 f16;
typedef _Float16 f16x8 __attribute__((ext_vector_type(8)));
typedef float f32x4 __attribute__((ext_vector_type(4)));

static constexpr int N_ = 8, C_ = 256, c_ = 128, L_ = 4096;

#define DEVI __device__ __forceinline__

DEVI f16x8 ldg8(const f16* p){ return *reinterpret_cast<const f16x8*>(p); }
DEVI f32x4 mfma16(f16x8 a, f16x8 b, f32x4 c){
  return __builtin_amdgcn_mfma_f32_16x16x32_f16(a, b, c, 0, 0, 0);
}
DEVI float silu(float x){ return x / (1.f + __expf(-x)); }

// ---------------- weight fp32 -> fp16 ----------------
__global__ __launch_bounds__(256) void prep_weights(const float* __restrict__ wq,
    const float* __restrict__ wk, const float* __restrict__ wv,
    const float* __restrict__ wo, f16* __restrict__ dst){
  int i = blockIdx.x * 256 + threadIdx.x;   // 131072 total
  int off = i & 32767;
  const float* s;
  switch (i >> 15){
    case 0:  s = wq; break;
    case 1:  s = wk; break;
    case 2:  s = wv; break;
    default: s = wo; break;
  }
  dst[i] = (f16)s[off];
}

// ---------------- group-norm stats ----------------
__global__ __launch_bounds__(256) void gn_stats(const float* __restrict__ x,
                                                float* __restrict__ st){
  int n = blockIdx.x >> 5, g = blockIdx.x & 31;
  const float* base = x + (size_t)(n * C_ + g * 8) * L_;   // 8 ch * 4096
  float s = 0.f, ss = 0.f;
  for (int it = 0; it < 32; ++it){
    float4 v = *reinterpret_cast<const float4*>(base + it * 1024 + threadIdx.x * 4);
    s  += v.x + v.y + v.z + v.w;
    ss += v.x * v.x + v.y * v.y + v.z * v.z + v.w * v.w;
  }
  #pragma unroll
  for (int m = 1; m <= 32; m <<= 1){ s += __shfl_xor(s, m); ss += __shfl_xor(ss, m); }
  __shared__ float red[8];
  int w = threadIdx.x >> 6;
  if ((threadIdx.x & 63) == 0){ red[w] = s; red[4 + w] = ss; }
  __syncthreads();
  if (threadIdx.x == 0){
    s  = red[0] + red[1] + red[2] + red[3];
    ss = red[4] + red[5] + red[6] + red[7];
    float mean = s * (1.f / 32768.f);
    float var  = ss * (1.f / 32768.f) - mean * mean;
    float2 o; o.x = mean; o.y = rsqrtf(var + 1e-5f);
    reinterpret_cast<float2*>(st)[blockIdx.x] = o;
  }
}

// ------------- GN apply + SiLU + transpose: x[N,C,L] f32 -> fT[N,L,C] f16 -------------
__global__ __launch_bounds__(256) void gn_apply(const float* __restrict__ x,
    const float* __restrict__ st, const float* __restrict__ gw,
    const float* __restrict__ gb, f16* __restrict__ fT){
  int n = blockIdx.z, c0 = blockIdx.y * 64, l0 = blockIdx.x * 64;
  __shared__ f16 tile[64][72];
  int t = threadIdx.x;
  int cr = t >> 4, lc = (t & 15) * 4;
  const float* xb = x + (size_t)(n * C_ + c0) * L_ + l0;
  #pragma unroll
  for (int p = 0; p < 4; ++p){
    int cc = cr + p * 16;
    int ch = c0 + cc;
    float2 ms = reinterpret_cast<const float2*>(st)[n * 32 + (ch >> 3)];
    float w = gw[ch], b = gb[ch];
    float4 v = *reinterpret_cast<const float4*>(xb + (size_t)cc * L_ + lc);
    float f0 = (v.x - ms.x) * ms.y * w + b;
    float f1 = (v.y - ms.x) * ms.y * w + b;
    float f2 = (v.z - ms.x) * ms.y * w + b;
    float f3 = (v.w - ms.x) * ms.y * w + b;
    tile[cc][lc + 0] = (f16)silu(f0);
    tile[cc][lc + 1] = (f16)silu(f1);
    tile[cc][lc + 2] = (f16)silu(f2);
    tile[cc][lc + 3] = (f16)silu(f3);
  }
  __syncthreads();
  int lr = t >> 2, cq = (t & 3) * 16;
  f16 tmp[16];
  #pragma unroll
  for (int e = 0; e < 16; ++e) tmp[e] = tile[cq + e][lr];
  f16* o = fT + (size_t)(n * L_ + l0 + lr) * C_ + c0 + cq;
  *reinterpret_cast<f16x8*>(o)     = *reinterpret_cast<f16x8*>(tmp);
  *reinterpret_cast<f16x8*>(o + 8) = *reinterpret_cast<f16x8*>(tmp + 8);
}

// ------------- generic MFMA GEMM: D[i][j] = sum_k A[i][k]*B[j][k] (+epilogue) -------------
// EPI 1: f16 out, + bias[i]      (v projection)
// EPI 2: f32 out, + bias[i] + resid (output projection + residual)
// EPI 3: f16 out, fused q/k: j<128 -> outv+bias[j], j>=128 -> outv2+bias2[j-128]
template<int EPI>
__global__ __launch_bounds__(256) void proj(const f16* __restrict__ A, size_t a_nstr,
    const f16* __restrict__ B, size_t b_nstr, const float* __restrict__ bias,
    void* __restrict__ outv, size_t o_nstr, int ldo,
    const float* __restrict__ resid, size_t r_nstr, int Ks,
    const float* __restrict__ bias2, void* __restrict__ outv2){
  int n = blockIdx.z;
  int i0 = blockIdx.x * 64;
  int w  = threadIdx.x >> 6;
  int jw = blockIdx.y * 128 + w * 32;
  int lane = threadIdx.x & 63, l15 = lane & 15, g4 = lane >> 4;
  const f16* Ab = A + (size_t)n * a_nstr;
  const f16* Bb = B + (size_t)n * b_nstr;
  int K = Ks * 32;
  f32x4 acc[4][2];
  #pragma unroll
  for (int mf = 0; mf < 4; ++mf)
    #pragma unroll
    for (int nf = 0; nf < 2; ++nf) acc[mf][nf] = (f32x4){0.f, 0.f, 0.f, 0.f};

  for (int ks = 0; ks < Ks; ++ks){
    int kk = ks * 32 + 8 * g4;
    f16x8 a[4], b[2];
    #pragma unroll
    for (int mf = 0; mf < 4; ++mf)
      a[mf] = ldg8(Ab + (size_t)(i0 + 16 * mf + l15) * K + kk);
    #pragma unroll
    for (int nf = 0; nf < 2; ++nf)
      b[nf] = ldg8(Bb + (size_t)(jw + 16 * nf + l15) * K + kk);
    #pragma unroll
    for (int mf = 0; mf < 4; ++mf)
      #pragma unroll
      for (int nf = 0; nf < 2; ++nf)
        acc[mf][nf] = mfma16(a[mf], b[nf], acc[mf][nf]);
  }

  #pragma unroll
  for (int mf = 0; mf < 4; ++mf){
    #pragma unroll
    for (int nf = 0; nf < 2; ++nf){
      int j = jw + 16 * nf + l15;
      #pragma unroll
      for (int r = 0; r < 4; ++r){
        int i = i0 + 16 * mf + 4 * g4 + r;
        float v = acc[mf][nf][r];
        if (EPI == 1){
          ((f16*)outv)[(size_t)n * o_nstr + (size_t)i * ldo + j] = (f16)(v + bias[i]);
        } else if (EPI == 2){
          size_t oidx = (size_t)n * o_nstr + (size_t)i * ldo + j;
          ((float*)outv)[oidx] = v + bias[i] + resid[(size_t)n * r_nstr + (size_t)i * ldo + j];
        } else {  // EPI 3
          if (j < 128)
            ((f16*)outv)[(size_t)n * o_nstr + (size_t)i * ldo + j] = (f16)(v + bias[j]);
          else
            ((f16*)outv2)[(size_t)n * o_nstr + (size_t)i * ldo + (j - 128)] = (f16)(v + bias2[j - 128]);
        }
      }
    }
  }
}

// ------------- flash attention: Q[N,L,128], K[N,L,128], V[N,128,L] -> silu(O/l)[N,L,128] -------------
// Round-9 change vs round 8: __launch_bounds__(256, 2) gives the register
// allocator a 256-VGPR budget so the async-staged kreg/vreg stay in registers.
// Round 8's plain (256) bound made the allocator pick 96 VGPR and spill the
// staging arrays to scratch: WRITE_SIZE 8MB -> 601MB, flash 195 -> 400us.
// 2 blocks/CU is already the grid limit (512 blocks / 256 CUs), so the cap
// costs no occupancy.
__global__ __launch_bounds__(256, 2) void flash(const f16* __restrict__ Qg,
    const f16* __restrict__ Kg, const f16* __restrict__ Vg, f16* __restrict__ Og){
  __shared__ char Ksh[16384];   // [64 j][128 d] f16, 16B-swizzled
  __shared__ char Vsh[16384];   // [128 d][64 j] f16, 16B-swizzled
  __shared__ char Psh[8192];    // 4 waves x [16 i][64 j] f16, swizzled
  int n = blockIdx.y;
  int q0 = blockIdx.x * 64;
  int tid = threadIdx.x;
  int w = tid >> 6, lane = tid & 63, l15 = lane & 15, g4 = lane >> 4;
  int qb = q0 + w * 16;

  const f16* Qn = Qg + (size_t)n * L_ * 128;
  const f16* Kn = Kg + (size_t)n * L_ * 128;
  const f16* Vn = Vg + (size_t)n * 128 * L_;

  f16x8 qf[4];
  #pragma unroll
  for (int ks = 0; ks < 4; ++ks)
    qf[ks] = ldg8(Qn + (size_t)(qb + l15) * 128 + ks * 32 + 8 * g4);

  f32x4 o[8];
  #pragma unroll
  for (int nf = 0; nf < 8; ++nf) o[nf] = (f32x4){0.f, 0.f, 0.f, 0.f};
  float mrow[4], lpart[4];
  #pragma unroll
  for (int r = 0; r < 4; ++r){ mrow[r] = -1e30f; lpart[r] = 0.f; }

  // prologue: stage tile 0 into registers
  float4 kreg[4], vreg[4];
  #pragma unroll
  for (int it = 0; it < 4; ++it){
    int cid = it * 256 + tid; int j = cid >> 4, c = cid & 15;
    kreg[it] = *reinterpret_cast<const float4*>(Kn + (size_t)j * 128 + c * 8);
  }
  #pragma unroll
  for (int it = 0; it < 4; ++it){
    int cid = it * 256 + tid; int d = cid >> 3, c = cid & 7;
    vreg[it] = *reinterpret_cast<const float4*>(Vn + (size_t)d * L_ + c * 8);
  }

  for (int t = 0; t < 64; ++t){
    // write staged regs -> LDS (prev compute finished at tail barrier)
    #pragma unroll
    for (int it = 0; it < 4; ++it){
      int cid = it * 256 + tid; int j = cid >> 4, c = cid & 15;
      *reinterpret_cast<float4*>(Ksh + j * 256 + ((c * 16) ^ ((j & 7) << 4))) = kreg[it];
    }
    #pragma unroll
    for (int it = 0; it < 4; ++it){
      int cid = it * 256 + tid; int d = cid >> 3, c = cid & 7;
      *reinterpret_cast<float4*>(Vsh + d * 128 + ((c * 16) ^ ((d & 7) << 4))) = vreg[it];
    }
    __syncthreads();

    // issue next tile's global loads; latency hides under compute below
    if (t + 1 < 64){
      #pragma unroll
      for (int it = 0; it < 4; ++it){
        int cid = it * 256 + tid; int j = cid >> 4, c = cid & 15;
        kreg[it] = *reinterpret_cast<const float4*>(Kn + (size_t)((t + 1) * 64 + j) * 128 + c * 8);
      }
      #pragma unroll
      for (int it = 0; it < 4; ++it){
        int cid = it * 256 + tid; int d = cid >> 3, c = cid & 7;
        vreg[it] = *reinterpret_cast<const float4*>(Vn + (size_t)d * L_ + (t + 1) * 64 + c * 8);
      }
    }

    // S = Q K^T : per wave 16 i x 64 j
    f32x4 s[4];
    #pragma unroll
    for (int nf = 0; nf < 4; ++nf) s[nf] = (f32x4){0.f, 0.f, 0.f, 0.f};
    #pragma unroll
    for (int ks = 0; ks < 4; ++ks){
      #pragma unroll
      for (int nf = 0; nf < 4; ++nf){
        int j = 16 * nf + l15;
        f16x8 kf = *reinterpret_cast<const f16x8*>(Ksh + j * 256 + ((64 * ks + 16 * g4) ^ ((j & 7) << 4)));
        s[nf] = mfma16(qf[ks], kf, s[nf]);
      }
    }

    // defer-max online softmax (row i = 4*g4 + r; 16 lanes sharing g4 hold the row)
    float pm[4];
    #pragma unroll
    for (int r = 0; r < 4; ++r)
      pm[r] = fmaxf(fmaxf(s[0][r], s[1][r]), fmaxf(s[2][r], s[3][r]));
    bool ex = (pm[0] > mrow[0] + 8.f) | (pm[1] > mrow[1] + 8.f) |
              (pm[2] > mrow[2] + 8.f) | (pm[3] > mrow[3] + 8.f);
    if (__any(ex)){
      #pragma unroll
      for (int r = 0; r < 4; ++r){
        float m = pm[r];
        m = fmaxf(m, __shfl_xor(m, 1));
        m = fmaxf(m, __shfl_xor(m, 2));
        m = fmaxf(m, __shfl_xor(m, 4));
        m = fmaxf(m, __shfl_xor(m, 8));
        float mn = fmaxf(mrow[r], m);
        float sc = __expf(mrow[r] - mn);
        mrow[r] = mn;
        lpart[r] *= sc;
        #pragma unroll
        for (int nf = 0; nf < 8; ++nf) o[nf][r] *= sc;
      }
    }
    #pragma unroll
    for (int nf = 0; nf < 4; ++nf)
      #pragma unroll
      for (int r = 0; r < 4; ++r)
        s[nf][r] = __expf(s[nf][r] - mrow[r]);
    #pragma unroll
    for (int r = 0; r < 4; ++r)
      lpart[r] += (s[0][r] + s[1][r]) + (s[2][r] + s[3][r]);

    // write P (f16) to this wave's LDS region [16 i][128B row]
    char* pb = Psh + w * 2048;
    #pragma unroll
    for (int nf = 0; nf < 4; ++nf)
      #pragma unroll
      for (int r = 0; r < 4; ++r){
        int i = 4 * g4 + r;
        int jj = 16 * nf + l15;
        *reinterpret_cast<f16*>(pb + i * 128 + ((2 * jj) ^ ((i & 7) << 4))) = (f16)s[nf][r];
      }

    // PV: O += P V
    #pragma unroll
    for (int ks = 0; ks < 2; ++ks){
      f16x8 pa = *reinterpret_cast<const f16x8*>(pb + l15 * 128 + ((64 * ks + 16 * g4) ^ ((l15 & 7) << 4)));
      #pragma unroll
      for (int nf = 0; nf < 8; ++nf){
        int d = 16 * nf + l15;
        f16x8 vf = *reinterpret_cast<const f16x8*>(Vsh + d * 128 + ((64 * ks + 16 * g4) ^ ((d & 7) << 4)));
        o[nf] = mfma16(pa, vf, o[nf]);
      }
    }
    __syncthreads();
  }

  // epilogue: reduce row-sum partials across the 16 lanes, then g = silu(O / l)
  float lrow[4];
  #pragma unroll
  for (int r = 0; r < 4; ++r){
    float rs = lpart[r];
    rs += __shfl_xor(rs, 1);
    rs += __shfl_xor(rs, 2);
    rs += __shfl_xor(rs, 4);
    rs += __shfl_xor(rs, 8);
    lrow[r] = rs;
  }
  f16* Ob = Og + (size_t)n * L_ * 128;
  #pragma unroll
  for (int r = 0; r < 4; ++r){
    float inv = 1.f / lrow[r];
    #pragma unroll
    for (int nf = 0; nf < 8; ++nf){
      float val = o[nf][r] * inv;
      Ob[(size_t)(qb + 4 * g4 + r) * 128 + 16 * nf + l15] = (f16)silu(val);
    }
  }
}

extern "C" void kernel_launch(void* const* d_in, const int* in_sizes, int n_in,
                              void* d_out, int out_size, void* d_ws, size_t ws_size,
                              hipStream_t stream){
  const float* x   = (const float*)d_in[0];
  const float* gnw = (const float*)d_in[1];
  const float* gnb = (const float*)d_in[2];
  const float* wq  = (const float*)d_in[3];
  const float* bq  = (const float*)d_in[4];
  const float* wk  = (const float*)d_in[5];
  const float* bk  = (const float*)d_in[6];
  const float* wv  = (const float*)d_in[7];
  const float* bv  = (const float*)d_in[8];
  const float* wo  = (const float*)d_in[9];
  const float* bo  = (const float*)d_in[10];
  float* out = (float*)d_out;

  char* ws = (char*)d_ws;
  f16* fT   = (f16*)(ws);                          // 16 MB  [N,L,C]
  f16* q    = (f16*)(ws + ((size_t)16 << 20));     // 8 MB   [N,L,128]
  f16* k    = (f16*)(ws + ((size_t)24 << 20));     // 8 MB   [N,L,128]
  f16* v    = (f16*)(ws + ((size_t)32 << 20));     // 8 MB   [N,128,L]
  f16* gbuf = (f16*)(ws + ((size_t)40 << 20));     // 8 MB   [N,L,128]
  f16* wh   = (f16*)(ws + ((size_t)48 << 20));     // 256 KB: wq|wk|wv|wo f16
  float* st = (float*)(ws + ((size_t)49 << 20));   // 2 KB

  prep_weights<<<512, 256, 0, stream>>>(wq, wk, wv, wo, wh);
  gn_stats<<<256, 256, 0, stream>>>(x, st);
  gn_apply<<<dim3(64, 4, 8), 256, 0, stream>>>(x, st, gnw, gnb, fT);

  // fused q,k: D[l][j] = sum_c fT[l][c] * [wq;wk][j][c], j in [0,256)
  proj<3><<<dim3(64, 2, 8), 256, 0, stream>>>(fT, (size_t)L_ * C_, wh, 0, bq,
                                              q, (size_t)L_ * c_, c_, nullptr, 0, 8, bk, k);
  // v: D[o][l] = sum_c wv[o][c] * fT[l][c]
  proj<1><<<dim3(2, 32, 8), 256, 0, stream>>>(wh + 65536, 0, fT, (size_t)L_ * C_, bv,
                                              v, (size_t)c_ * L_, L_, nullptr, 0, 8, nullptr, nullptr);
  flash<<<dim3(64, 8), 256, 0, stream>>>(q, k, v, gbuf);
  // out: D[o][l] = sum_d wo[o][d] * g[l][d] + bo[o] + x
  proj<2><<<dim3(4, 32, 8), 256, 0, stream>>>(wh + 98304, 0, gbuf, (size_t)L_ * c_, bo,
                                              out, (size_t)C_ * L_, L_, x, (size_t)C_ * L_, 4, nullptr, nullptr);
}

// Round 13
// 288.194 us; speedup vs baseline: 1.9206x; 1.5954x over previous
//
#include <hip/hip_runtime.h>

typedef _Float16 f16;
typedef _Float16 f16x8 __attribute__((ext_vector_type(8)));
typedef float f32x4 __attribute__((ext_vector_type(4)));

static constexpr int N_ = 8, C_ = 256, c_ = 128, L_ = 4096;

#define DEVI __device__ __forceinline__

DEVI f16x8 ldg8(const f16* p){ return *reinterpret_cast<const f16x8*>(p); }
DEVI f32x4 mfma16(f16x8 a, f16x8 b, f32x4 c){
  return __builtin_amdgcn_mfma_f32_16x16x32_f16(a, b, c, 0, 0, 0);
}
DEVI float silu(float x){ return x / (1.f + __expf(-x)); }

// global->LDS DMA, 16B per lane; LDS dest is wave-uniform base + lane*16
#define GLOAD_LDS16(gaddr, laddr) \
  __builtin_amdgcn_global_load_lds( \
      (const __attribute__((address_space(1))) void*)(gaddr), \
      (__attribute__((address_space(3))) void*)(laddr), 16, 0, 0)

// ---------------- weight fp32 -> fp16 ----------------
__global__ __launch_bounds__(256) void prep_weights(const float* __restrict__ wq,
    const float* __restrict__ wk, const float* __restrict__ wv,
    const float* __restrict__ wo, f16* __restrict__ dst){
  int i = blockIdx.x * 256 + threadIdx.x;   // 131072 total
  int off = i & 32767;
  const float* s;
  switch (i >> 15){
    case 0:  s = wq; break;
    case 1:  s = wk; break;
    case 2:  s = wv; break;
    default: s = wo; break;
  }
  dst[i] = (f16)s[off];
}

// ---------------- group-norm stats ----------------
__global__ __launch_bounds__(256) void gn_stats(const float* __restrict__ x,
                                                float* __restrict__ st){
  int n = blockIdx.x >> 5, g = blockIdx.x & 31;
  const float* base = x + (size_t)(n * C_ + g * 8) * L_;   // 8 ch * 4096
  float s = 0.f, ss = 0.f;
  for (int it = 0; it < 32; ++it){
    float4 v = *reinterpret_cast<const float4*>(base + it * 1024 + threadIdx.x * 4);
    s  += v.x + v.y + v.z + v.w;
    ss += v.x * v.x + v.y * v.y + v.z * v.z + v.w * v.w;
  }
  #pragma unroll
  for (int m = 1; m <= 32; m <<= 1){ s += __shfl_xor(s, m); ss += __shfl_xor(ss, m); }
  __shared__ float red[8];
  int w = threadIdx.x >> 6;
  if ((threadIdx.x & 63) == 0){ red[w] = s; red[4 + w] = ss; }
  __syncthreads();
  if (threadIdx.x == 0){
    s  = red[0] + red[1] + red[2] + red[3];
    ss = red[4] + red[5] + red[6] + red[7];
    float mean = s * (1.f / 32768.f);
    float var  = ss * (1.f / 32768.f) - mean * mean;
    float2 o; o.x = mean; o.y = rsqrtf(var + 1e-5f);
    reinterpret_cast<float2*>(st)[blockIdx.x] = o;
  }
}

// ------------- GN apply + SiLU + transpose: x[N,C,L] f32 -> fT[N,L,C] f16 -------------
__global__ __launch_bounds__(256) void gn_apply(const float* __restrict__ x,
    const float* __restrict__ st, const float* __restrict__ gw,
    const float* __restrict__ gb, f16* __restrict__ fT){
  int n = blockIdx.z, c0 = blockIdx.y * 64, l0 = blockIdx.x * 64;
  __shared__ f16 tile[64][72];
  int t = threadIdx.x;
  int cr = t >> 4, lc = (t & 15) * 4;
  const float* xb = x + (size_t)(n * C_ + c0) * L_ + l0;
  #pragma unroll
  for (int p = 0; p < 4; ++p){
    int cc = cr + p * 16;
    int ch = c0 + cc;
    float2 ms = reinterpret_cast<const float2*>(st)[n * 32 + (ch >> 3)];
    float w = gw[ch], b = gb[ch];
    float4 v = *reinterpret_cast<const float4*>(xb + (size_t)cc * L_ + lc);
    float f0 = (v.x - ms.x) * ms.y * w + b;
    float f1 = (v.y - ms.x) * ms.y * w + b;
    float f2 = (v.z - ms.x) * ms.y * w + b;
    float f3 = (v.w - ms.x) * ms.y * w + b;
    tile[cc][lc + 0] = (f16)silu(f0);
    tile[cc][lc + 1] = (f16)silu(f1);
    tile[cc][lc + 2] = (f16)silu(f2);
    tile[cc][lc + 3] = (f16)silu(f3);
  }
  __syncthreads();
  int lr = t >> 2, cq = (t & 3) * 16;
  f16 tmp[16];
  #pragma unroll
  for (int e = 0; e < 16; ++e) tmp[e] = tile[cq + e][lr];
  f16* o = fT + (size_t)(n * L_ + l0 + lr) * C_ + c0 + cq;
  *reinterpret_cast<f16x8*>(o)     = *reinterpret_cast<f16x8*>(tmp);
  *reinterpret_cast<f16x8*>(o + 8) = *reinterpret_cast<f16x8*>(tmp + 8);
}

// ------------- generic MFMA GEMM: D[i][j] = sum_k A[i][k]*B[j][k] (+epilogue) -------------
// EPI 1: f16 out, + bias[i]      (v projection)
// EPI 2: f32 out, + bias[i] + resid (output projection + residual)
// EPI 3: f16 out, fused q/k: j<128 -> outv+bias[j], j>=128 -> outv2+bias2[j-128]
template<int EPI>
__global__ __launch_bounds__(256) void proj(const f16* __restrict__ A, size_t a_nstr,
    const f16* __restrict__ B, size_t b_nstr, const float* __restrict__ bias,
    void* __restrict__ outv, size_t o_nstr, int ldo,
    const float* __restrict__ resid, size_t r_nstr, int Ks,
    const float* __restrict__ bias2, void* __restrict__ outv2){
  int n = blockIdx.z;
  int i0 = blockIdx.x * 64;
  int w  = threadIdx.x >> 6;
  int jw = blockIdx.y * 128 + w * 32;
  int lane = threadIdx.x & 63, l15 = lane & 15, g4 = lane >> 4;
  const f16* Ab = A + (size_t)n * a_nstr;
  const f16* Bb = B + (size_t)n * b_nstr;
  int K = Ks * 32;
  f32x4 acc[4][2];
  #pragma unroll
  for (int mf = 0; mf < 4; ++mf)
    #pragma unroll
    for (int nf = 0; nf < 2; ++nf) acc[mf][nf] = (f32x4){0.f, 0.f, 0.f, 0.f};

  for (int ks = 0; ks < Ks; ++ks){
    int kk = ks * 32 + 8 * g4;
    f16x8 a[4], b[2];
    #pragma unroll
    for (int mf = 0; mf < 4; ++mf)
      a[mf] = ldg8(Ab + (size_t)(i0 + 16 * mf + l15) * K + kk);
    #pragma unroll
    for (int nf = 0; nf < 2; ++nf)
      b[nf] = ldg8(Bb + (size_t)(jw + 16 * nf + l15) * K + kk);
    #pragma unroll
    for (int mf = 0; mf < 4; ++mf)
      #pragma unroll
      for (int nf = 0; nf < 2; ++nf)
        acc[mf][nf] = mfma16(a[mf], b[nf], acc[mf][nf]);
  }

  #pragma unroll
  for (int mf = 0; mf < 4; ++mf){
    #pragma unroll
    for (int nf = 0; nf < 2; ++nf){
      int j = jw + 16 * nf + l15;
      #pragma unroll
      for (int r = 0; r < 4; ++r){
        int i = i0 + 16 * mf + 4 * g4 + r;
        float v = acc[mf][nf][r];
        if (EPI == 1){
          ((f16*)outv)[(size_t)n * o_nstr + (size_t)i * ldo + j] = (f16)(v + bias[i]);
        } else if (EPI == 2){
          size_t oidx = (size_t)n * o_nstr + (size_t)i * ldo + j;
          ((float*)outv)[oidx] = v + bias[i] + resid[(size_t)n * r_nstr + (size_t)i * ldo + j];
        } else {  // EPI 3
          if (j < 128)
            ((f16*)outv)[(size_t)n * o_nstr + (size_t)i * ldo + j] = (f16)(v + bias[j]);
          else
            ((f16*)outv2)[(size_t)n * o_nstr + (size_t)i * ldo + (j - 128)] = (f16)(v + bias2[j - 128]);
        }
      }
    }
  }
}

// ------------- flash attention: Q[N,L,128], K[N,L,128], V[N,128,L] -> silu(O/l)[N,L,128] -------------
// Round-11: async staging via global_load_lds DMA + double-buffered LDS.
// Register staging (rounds 8/10) spilled regardless of launch_bounds
// (VGPR 96/88, WRITE_SIZE ~0.5GB scratch) -- DMA needs no VGPRs at all and
// also removes the synchronous ds_write phase from the barrier window.
// LDS dest is linear (base+lane*16, m104), so the XOR swizzle is pre-applied
// to the per-lane GLOBAL source chunk (c ^ (row&7)); read side unchanged
// (rule #21: same involution on source and read).
__global__ __launch_bounds__(256) void flash(const f16* __restrict__ Qg,
    const f16* __restrict__ Kg, const f16* __restrict__ Vg, f16* __restrict__ Og){
  __shared__ char Ksh[2][16384];  // [64 j][16 chunks of 16B], chunk c holds global chunk c^(j&7)
  __shared__ char Vsh[2][16384];  // [128 d][8 chunks of 16B], chunk c holds global chunk c^(d&7)
  __shared__ char Psh[8192];      // 4 waves x [16 i][64 j] f16, swizzled
  int n = blockIdx.y;
  int q0 = blockIdx.x * 64;
  int tid = threadIdx.x;
  int w = tid >> 6, lane = tid & 63, l15 = lane & 15, g4 = lane >> 4;
  int qb = q0 + w * 16;

  const f16* Qn = Qg + (size_t)n * L_ * 128;
  const f16* Kn = Kg + (size_t)n * L_ * 128;
  const f16* Vn = Vg + (size_t)n * 128 * L_;

  f16x8 qf[4];
  #pragma unroll
  for (int ks = 0; ks < 4; ++ks)
    qf[ks] = ldg8(Qn + (size_t)(qb + l15) * 128 + ks * 32 + 8 * g4);

  f32x4 o[8];
  #pragma unroll
  for (int nf = 0; nf < 8; ++nf) o[nf] = (f32x4){0.f, 0.f, 0.f, 0.f};
  float mrow[4], lpart[4];
  #pragma unroll
  for (int r = 0; r < 4; ++r){ mrow[r] = -1e30f; lpart[r] = 0.f; }

  // K-tile stage: per wave 4 DMA calls of 1KB; lane's LDS slot = base+lane*16
  // covers row j = call*16 + w*4 + (lane>>4), chunk c = lane&15; source chunk
  // is pre-swizzled c^(j&7).
  auto stageK = [&](char* Kb, int t){
    #pragma unroll
    for (int call = 0; call < 4; ++call){
      int j = call * 16 + w * 4 + (lane >> 4);
      int cg = (lane & 15) ^ (j & 7);
      GLOAD_LDS16(Kn + (size_t)(t * 64 + j) * 128 + cg * 8, Kb + call * 4096 + w * 1024);
    }
  };
  // V-tile stage: row d = call*32 + w*8 + (lane>>3), chunk c = lane&7,
  // source chunk c^(d&7).
  auto stageV = [&](char* Vb, int t){
    #pragma unroll
    for (int call = 0; call < 4; ++call){
      int d = call * 32 + w * 8 + (lane >> 3);
      int cg = (lane & 7) ^ (d & 7);
      GLOAD_LDS16(Vn + (size_t)d * L_ + t * 64 + cg * 8, Vb + call * 4096 + w * 1024);
    }
  };

  stageK(Ksh[0], 0);
  stageV(Vsh[0], 0);
  __syncthreads();   // emits s_waitcnt vmcnt(0) before barrier -> DMA visible

  int cur = 0;
  for (int t = 0; t < 64; ++t){
    // issue next tile's DMA into the other buffer; stays in flight during compute
    if (t + 1 < 64){
      stageK(Ksh[cur ^ 1], t + 1);
      stageV(Vsh[cur ^ 1], t + 1);
    }
    const char* Kb = Ksh[cur];
    const char* Vb = Vsh[cur];

    // S = Q K^T : per wave 16 i x 64 j
    f32x4 s[4];
    #pragma unroll
    for (int nf = 0; nf < 4; ++nf) s[nf] = (f32x4){0.f, 0.f, 0.f, 0.f};
    #pragma unroll
    for (int ks = 0; ks < 4; ++ks){
      #pragma unroll
      for (int nf = 0; nf < 4; ++nf){
        int j = 16 * nf + l15;
        f16x8 kf = *reinterpret_cast<const f16x8*>(Kb + j * 256 + ((64 * ks + 16 * g4) ^ ((j & 7) << 4)));
        s[nf] = mfma16(qf[ks], kf, s[nf]);
      }
    }

    // defer-max online softmax (row i = 4*g4 + r; 16 lanes sharing g4 hold the row)
    float pm[4];
    #pragma unroll
    for (int r = 0; r < 4; ++r)
      pm[r] = fmaxf(fmaxf(s[0][r], s[1][r]), fmaxf(s[2][r], s[3][r]));
    bool ex = (pm[0] > mrow[0] + 8.f) | (pm[1] > mrow[1] + 8.f) |
              (pm[2] > mrow[2] + 8.f) | (pm[3] > mrow[3] + 8.f);
    if (__any(ex)){
      #pragma unroll
      for (int r = 0; r < 4; ++r){
        float m = pm[r];
        m = fmaxf(m, __shfl_xor(m, 1));
        m = fmaxf(m, __shfl_xor(m, 2));
        m = fmaxf(m, __shfl_xor(m, 4));
        m = fmaxf(m, __shfl_xor(m, 8));
        float mn = fmaxf(mrow[r], m);
        float sc = __expf(mrow[r] - mn);
        mrow[r] = mn;
        lpart[r] *= sc;
        #pragma unroll
        for (int nf = 0; nf < 8; ++nf) o[nf][r] *= sc;
      }
    }
    #pragma unroll
    for (int nf = 0; nf < 4; ++nf)
      #pragma unroll
      for (int r = 0; r < 4; ++r)
        s[nf][r] = __expf(s[nf][r] - mrow[r]);
    #pragma unroll
    for (int r = 0; r < 4; ++r)
      lpart[r] += (s[0][r] + s[1][r]) + (s[2][r] + s[3][r]);

    // write P (f16) to this wave's LDS region [16 i][128B row]
    char* pb = Psh + w * 2048;
    #pragma unroll
    for (int nf = 0; nf < 4; ++nf)
      #pragma unroll
      for (int r = 0; r < 4; ++r){
        int i = 4 * g4 + r;
        int jj = 16 * nf + l15;
        *reinterpret_cast<f16*>(pb + i * 128 + ((2 * jj) ^ ((i & 7) << 4))) = (f16)s[nf][r];
      }

    // PV: O += P V
    #pragma unroll
    for (int ks = 0; ks < 2; ++ks){
      f16x8 pa = *reinterpret_cast<const f16x8*>(pb + l15 * 128 + ((64 * ks + 16 * g4) ^ ((l15 & 7) << 4)));
      #pragma unroll
      for (int nf = 0; nf < 8; ++nf){
        int d = 16 * nf + l15;
        f16x8 vf = *reinterpret_cast<const f16x8*>(Vb + d * 128 + ((64 * ks + 16 * g4) ^ ((d & 7) << 4)));
        o[nf] = mfma16(pa, vf, o[nf]);
      }
    }
    // barrier drains the in-flight DMA (vmcnt 0) and closes reads of buf cur
    __syncthreads();
    cur ^= 1;
  }

  // epilogue: reduce row-sum partials across the 16 lanes, then g = silu(O / l)
  float lrow[4];
  #pragma unroll
  for (int r = 0; r < 4; ++r){
    float rs = lpart[r];
    rs += __shfl_xor(rs, 1);
    rs += __shfl_xor(rs, 2);
    rs += __shfl_xor(rs, 4);
    rs += __shfl_xor(rs, 8);
    lrow[r] = rs;
  }
  f16* Ob = Og + (size_t)n * L_ * 128;
  #pragma unroll
  for (int r = 0; r < 4; ++r){
    float inv = 1.f / lrow[r];
    #pragma unroll
    for (int nf = 0; nf < 8; ++nf){
      float val = o[nf][r] * inv;
      Ob[(size_t)(qb + 4 * g4 + r) * 128 + 16 * nf + l15] = (f16)silu(val);
    }
  }
}

extern "C" void kernel_launch(void* const* d_in, const int* in_sizes, int n_in,
                              void* d_out, int out_size, void* d_ws, size_t ws_size,
                              hipStream_t stream){
  const float* x   = (const float*)d_in[0];
  const float* gnw = (const float*)d_in[1];
  const float* gnb = (const float*)d_in[2];
  const float* wq  = (const float*)d_in[3];
  const float* bq  = (const float*)d_in[4];
  const float* wk  = (const float*)d_in[5];
  const float* bk  = (const float*)d_in[6];
  const float* wv  = (const float*)d_in[7];
  const float* bv  = (const float*)d_in[8];
  const float* wo  = (const float*)d_in[9];
  const float* bo  = (const float*)d_in[10];
  float* out = (float*)d_out;

  char* ws = (char*)d_ws;
  f16* fT   = (f16*)(ws);                          // 16 MB  [N,L,C]
  f16* q    = (f16*)(ws + ((size_t)16 << 20));     // 8 MB   [N,L,128]
  f16* k    = (f16*)(ws + ((size_t)24 << 20));     // 8 MB   [N,L,128]
  f16* v    = (f16*)(ws + ((size_t)32 << 20));     // 8 MB   [N,128,L]
  f16* gbuf = (f16*)(ws + ((size_t)40 << 20));     // 8 MB   [N,L,128]
  f16* wh   = (f16*)(ws + ((size_t)48 << 20));     // 256 KB: wq|wk|wv|wo f16
  float* st = (float*)(ws + ((size_t)49 << 20));   // 2 KB

  prep_weights<<<512, 256, 0, stream>>>(wq, wk, wv, wo, wh);
  gn_stats<<<256, 256, 0, stream>>>(x, st);
  gn_apply<<<dim3(64, 4, 8), 256, 0, stream>>>(x, st, gnw, gnb, fT);

  // fused q,k: D[l][j] = sum_c fT[l][c] * [wq;wk][j][c], j in [0,256)
  proj<3><<<dim3(64, 2, 8), 256, 0, stream>>>(fT, (size_t)L_ * C_, wh, 0, bq,
                                              q, (size_t)L_ * c_, c_, nullptr, 0, 8, bk, k);
  // v: D[o][l] = sum_c wv[o][c] * fT[l][c]
  proj<1><<<dim3(2, 32, 8), 256, 0, stream>>>(wh + 65536, 0, fT, (size_t)L_ * C_, bv,
                                              v, (size_t)c_ * L_, L_, nullptr, 0, 8, nullptr, nullptr);
  flash<<<dim3(64, 8), 256, 0, stream>>>(q, k, v, gbuf);
  // out: D[o][l] = sum_d wo[o][d] * g[l][d] + bo[o] + x
  proj<2><<<dim3(4, 32, 8), 256, 0, stream>>>(wh + 98304, 0, gbuf, (size_t)L_ * c_, bo,
                                              out, (size_t)C_ * L_, L_, x, (size_t)C_ * L_, 4, nullptr, nullptr);
}